// Round 14
// baseline (1204.409 us; speedup 1.0000x reference)
//
#include <hip/hip_runtime.h>
#include <math.h>

// Problem constants
#define BB    4096   // batch
#define LL    30     // seq len
#define WW    5      // window
#define CC    40     // conv channels
#define HH    128    // lstm units
#define TT    3      // crf tags
#define KA    328    // 200 (features) + 128 (h)
#define NB    16     // batch rows per LSTM block (R14: halved -> 2 blocks/CU)
#define FSTR  232    // F row stride (u16): 7 K-chunks = 224 cols (200 real + 24 pad)
#define HSTR  136    // H row stride (u16): 128 cols + pad (16B-aligned rows)
#define CW    1056   // per-column W footprint in ushorts: 11 Ks * 3 s * 32 k

// Workspace layout (in floats)
#define WS_P    0                         // P'[3][30][40] conv collapsed + bn1 folded
#define WS_BC   3600                      // biasC[40]
#define WS_BG   3648                      // biasG[2][512]
#define WS_WFC  4672                      // Wfc[2][3][128]  (fc folded with bn2)
#define WS_EB   5440                      // ebias[3]
#define WS_WBF  5504                      // bf16 W [d][n][Ks][s][32]: 540672 floats
#define WS_EMIS (5504 + 540672)           // emis[2][B][L][3] partial emissions

typedef __bf16 bf16x8 __attribute__((ext_vector_type(8)));
typedef float  f32x4  __attribute__((ext_vector_type(4)));
typedef unsigned short u16x8 __attribute__((ext_vector_type(8)));

__device__ __forceinline__ float sigm(float x) {
    return __builtin_amdgcn_rcpf(1.0f + __expf(-x));
}
__device__ __forceinline__ float tanh_fast(float x) {
    return 2.0f * __builtin_amdgcn_rcpf(1.0f + __expf(-2.0f * x)) - 1.0f;
}
// bf16 round-to-nearest-even helpers
__device__ __forceinline__ unsigned short f2bf(float f) {
    unsigned u = __builtin_bit_cast(unsigned, f);
    return (unsigned short)((u + 0x7FFFu + ((u >> 16) & 1u)) >> 16);
}
__device__ __forceinline__ float bf2f(unsigned short h) {
    unsigned u = ((unsigned)h) << 16;
    return __builtin_bit_cast(float, u);
}

// ---------------------------------------------------------------------------
// Kernel 1: fold BN1 into conv tables, 3-term split-bf16 repack of LSTM
// weights ([d][n][Ks][s][32] — per-column offsets are load immediates),
// fold BN2 into FC. W k-map matches A-side: k<200 wih; 200..223 zero (F pad);
// 224..351 whh[k-224].  (unchanged from R13)
// ---------------------------------------------------------------------------
__global__ void prep_kernel(const float* __restrict__ emb, const float* __restrict__ conv_w,
                            const float* __restrict__ conv_b,
                            const float* __restrict__ bn1_g, const float* __restrict__ bn1_b,
                            const float* __restrict__ bn1_m, const float* __restrict__ bn1_v,
                            const float* __restrict__ w_ih_f, const float* __restrict__ w_hh_f,
                            const float* __restrict__ b_f,
                            const float* __restrict__ w_ih_b, const float* __restrict__ w_hh_b,
                            const float* __restrict__ b_b,
                            const float* __restrict__ bn2_g, const float* __restrict__ bn2_b,
                            const float* __restrict__ bn2_m, const float* __restrict__ bn2_v,
                            const float* __restrict__ fc_w, const float* __restrict__ fc_b,
                            float* __restrict__ ws)
{
    const int gid = blockIdx.x * blockDim.x + threadIdx.x;
    const int gsz = gridDim.x * blockDim.x;

    for (int idx = gid; idx < 3600; idx += gsz) {
        int k = idx / 1200, rem = idx % 1200, a = rem / 40, c = rem % 40;
        float s1 = bn1_g[c] / sqrtf(bn1_v[c] + 1e-5f);
        float acc = 0.f;
        for (int e = 0; e < 128; ++e)
            acc += emb[a * 128 + e] * conv_w[(c * 128 + e) * 3 + k];
        ws[WS_P + idx] = acc * s1;
    }
    for (int c = gid; c < CC; c += gsz) {
        float s1 = bn1_g[c] / sqrtf(bn1_v[c] + 1e-5f);
        ws[WS_BC + c] = (conv_b[c] - bn1_m[c]) * s1 + bn1_b[c];
    }
    for (int i = gid; i < 1024; i += gsz) {
        int d = i >> 9, g = i & 511;
        ws[WS_BG + i] = d ? b_b[g] : b_f[g];
    }
    for (int i = gid; i < 768; i += gsz) {
        int d = i / 384, r = i % 384, t = r / 128, u = r % 128;
        int j = d * 128 + u;
        float s2 = bn2_g[j] / sqrtf(bn2_v[j] + 1e-5f);
        ws[WS_WFC + i] = fc_w[t * 256 + j] * s2;
    }
    for (int t = gid; t < TT; t += gsz) {
        float acc = fc_b[t];
        for (int j = 0; j < 256; ++j) {
            float s2 = bn2_g[j] / sqrtf(bn2_v[j] + 1e-5f);
            acc += fc_w[t * 256 + j] * (bn2_b[j] - bn2_m[j] * s2);
        }
        ws[WS_EB + t] = acc;
    }
    // Wbf[d][n][Ks][s][32]: n = 4u+g; per column all Ks/s chunks contiguous.
    unsigned short* wsu = (unsigned short*)ws;
    for (int i = gid; i < 2 * 512 * CW; i += gsz) {
        int d = i / (512 * CW), r = i % (512 * CW);
        int n = r / CW, q = r % CW;
        int Ks = q / 96, t = q % 96, s = t / 32, k32 = t % 32;
        int k = Ks * 32 + k32;
        int u = n >> 2, g = n & 3, row = g * 128 + u;
        const float* wih = d ? w_ih_b : w_ih_f;
        const float* whh = d ? w_hh_b : w_hh_f;
        float w = (k < 200) ? wih[row * 200 + k]
                            : ((k >= 224) ? whh[row * 128 + (k - 224)] : 0.f);
        unsigned short t0 = f2bf(w);
        float r1 = w - bf2f(t0);
        unsigned short t1 = f2bf(r1);
        unsigned short t2 = f2bf(r1 - bf2f(t1));
        wsu[2 * WS_WBF + i] = (s == 0) ? t0 : ((s == 1) ? t1 : t2);
    }
}

// ---------------------------------------------------------------------------
// Kernel 2: fused features + BiLSTM (3-term split-bf16 MFMA) + emissions.
// R14: NB=16, 512 blocks = 2 dirs x 256 tiles, 2 blocks/CU (LDS ~72 KB),
// 4 waves/SIMD — independent blocks overlap GEMM with features/gates (R13's
// barrier-locked 1-block structure summed the pipes: 20.5K MFMA + 12.5K VALU
// + LDS + L2 = 59.6K cyc/step with only 53% combined utilization).
// Numerics identical (6 products, same order). mt dimension removed:
// lane (wv,quad,ml) owns units un[nt]=wv*16+nt*4+quad for batch row ml.
// ---------------------------------------------------------------------------
__global__ __launch_bounds__(512, 4)
void lstm_kernel(const int* __restrict__ x, float* __restrict__ ws)
{
    __shared__ unsigned short Fh[2][NB * FSTR], Fl[2][NB * FSTR], Fm[2][NB * FSTR];
    __shared__ unsigned short Hh[NB * HSTR], Hl[NB * HSTR], Hm[NB * HSTR];
    __shared__ float Pp_s[3600];
    __shared__ float Wfc_s[384];
    __shared__ float biasC_s[40];

    const int tid = threadIdx.x;
    const int d   = blockIdx.x & 1;
    const int b0  = (blockIdx.x >> 1) * NB;

    const unsigned short* __restrict__ Wb =
        (const unsigned short*)ws + 2 * WS_WBF + d * (512 * CW);
    float* emis = ws + WS_EMIS + d * (BB * LL * TT);

    for (int i = tid; i < 3600; i += 512) Pp_s[i] = ws[WS_P + i];
    for (int i = tid; i < 384;  i += 512) Wfc_s[i] = ws[WS_WFC + d * 384 + i];
    for (int i = tid; i < 40;   i += 512) biasC_s[i] = ws[WS_BC + i];
    // zero F (both buffers; covers K pads) and H (initial h=0)
    for (int i = tid; i < NB * FSTR; i += 512) {
        ((unsigned*)Fh)[i] = 0u; ((unsigned*)Fl)[i] = 0u; ((unsigned*)Fm)[i] = 0u;
    }
    for (int i = tid; i < NB * HSTR / 2; i += 512) {
        ((unsigned*)Hh)[i] = 0u; ((unsigned*)Hl)[i] = 0u; ((unsigned*)Hm)[i] = 0u;
    }

    const int lane = tid & 63;
    const int wv   = tid >> 6;          // 0..7: N-tile group (gate-cols 64*wv..)
    const int quad = lane >> 4;
    const int ml   = lane & 15;         // batch row

    // 4 W base pointers, one per nt; all further offsets are immediates.
    const unsigned short* __restrict__ Wn0 = Wb + (wv * 64 +  0 + ml) * CW + quad * 8;
    const unsigned short* __restrict__ Wn1 = Wb + (wv * 64 + 16 + ml) * CW + quad * 8;
    const unsigned short* __restrict__ Wn2 = Wb + (wv * 64 + 32 + ml) * CW + quad * 8;
    const unsigned short* __restrict__ Wn3 = Wb + (wv * 64 + 48 + ml) * CW + quad * 8;

    // this lane's units (one per nt) and their gate biases
    const float* bgp = ws + WS_BG + d * 512;
    int   un[4];
    float bIv[4], bFv[4], bGv[4], bOv[4];
    #pragma unroll
    for (int nt = 0; nt < 4; ++nt) {
        int u = wv * 16 + nt * 4 + quad;
        un[nt]  = u;
        bIv[nt] = bgp[u];
        bFv[nt] = bgp[128 + u];
        bGv[nt] = bgp[256 + u];
        bOv[nt] = bgp[384 + u];
    }

    float cst[4];
    #pragma unroll
    for (int nt = 0; nt < 4; ++nt) cst[nt] = 0.f;

    __syncthreads();

    // ---- feature computation into F buffer `buf` for seq position l ----
#define DO_FEATURES(LPOS, BUF)                                                 \
    for (int p = tid; p < NB * CC; p += 512) {                                 \
        int bb = p / CC, c = p % CC;                                           \
        const int* tok = x + (((b0 + bb) * LL) + (LPOS)) * WW;                 \
        int t0 = tok[0], t1 = tok[1], t2 = tok[2], t3 = tok[3], t4 = tok[4];   \
        float bc = biasC_s[c];                                                 \
        float a0 = bc + Pp_s[(30 + t0) * 40 + c] + Pp_s[(60 + t1) * 40 + c];   \
        float a1 = bc + Pp_s[t0 * 40 + c] + Pp_s[(30 + t1) * 40 + c] + Pp_s[(60 + t2) * 40 + c]; \
        float a2 = bc + Pp_s[t1 * 40 + c] + Pp_s[(30 + t2) * 40 + c] + Pp_s[(60 + t3) * 40 + c]; \
        float a3 = bc + Pp_s[t2 * 40 + c] + Pp_s[(30 + t3) * 40 + c] + Pp_s[(60 + t4) * 40 + c]; \
        float a4 = bc + Pp_s[t3 * 40 + c] + Pp_s[(30 + t4) * 40 + c];          \
        a0 = fmaxf(a0, 0.f); a1 = fmaxf(a1, 0.f); a2 = fmaxf(a2, 0.f);         \
        a3 = fmaxf(a3, 0.f); a4 = fmaxf(a4, 0.f);                              \
        float f[5];                                                            \
        f[0] = fmaxf(a0, a1);                                                  \
        f[1] = fmaxf(fmaxf(a0, a1), a2);                                       \
        f[2] = fmaxf(fmaxf(a1, a2), a3);                                       \
        f[3] = fmaxf(fmaxf(a2, a3), a4);                                       \
        f[4] = fmaxf(a3, a4);                                                  \
        int base = bb * FSTR + c * 5;                                          \
        _Pragma("unroll")                                                      \
        for (int j = 0; j < 5; ++j) {                                          \
            unsigned short h0 = f2bf(f[j]);                                    \
            float r1 = f[j] - bf2f(h0);                                        \
            unsigned short h1 = f2bf(r1);                                      \
            unsigned short h2 = f2bf(r1 - bf2f(h1));                           \
            Fh[BUF][base + j] = h0;                                            \
            Fl[BUF][base + j] = h1;                                            \
            Fm[BUF][base + j] = h2;                                            \
        }                                                                      \
    }

    // prologue: features for step 0
    {
        const int l0 = d ? (LL - 1) : 0;
        DO_FEATURES(l0, 0)
    }
    __syncthreads();

    for (int step = 0; step < LL; ++step) {
        const int fb = step & 1;

        // ================= Phase A: GEMM + features(t+1) + emissions(t-1) ==
        f32x4 acc[4];
        #pragma unroll
        for (int nt = 0; nt < 4; ++nt)
            acc[nt] = (f32x4){0.f, 0.f, 0.f, 0.f};

#define WLOAD(B, P, KS)                                                        \
        {                                                                      \
            B[0] = *(const bf16x8*)((P) + (KS) * 96);                          \
            B[1] = *(const bf16x8*)((P) + (KS) * 96 + 32);                     \
            B[2] = *(const bf16x8*)((P) + (KS) * 96 + 64);                     \
        }
        // D = W' * A'  (same 6 products, same order as R9-R13)
#define GEMM6(B, NT)                                                           \
        {                                                                      \
            acc[NT] = __builtin_amdgcn_mfma_f32_16x16x32_bf16(B[0], a0[0], acc[NT], 0, 0, 0); \
            acc[NT] = __builtin_amdgcn_mfma_f32_16x16x32_bf16(B[0], a0[1], acc[NT], 0, 0, 0); \
            acc[NT] = __builtin_amdgcn_mfma_f32_16x16x32_bf16(B[1], a0[0], acc[NT], 0, 0, 0); \
            acc[NT] = __builtin_amdgcn_mfma_f32_16x16x32_bf16(B[1], a0[1], acc[NT], 0, 0, 0); \
            acc[NT] = __builtin_amdgcn_mfma_f32_16x16x32_bf16(B[2], a0[0], acc[NT], 0, 0, 0); \
            acc[NT] = __builtin_amdgcn_mfma_f32_16x16x32_bf16(B[0], a0[2], acc[NT], 0, 0, 0); \
        }

        {
            bf16x8 bufA[3], bufB[3];
            WLOAD(bufA, Wn0, 0)

            #pragma unroll
            for (int Ks = 0; Ks < 11; ++Ks) {
                bf16x8 a0[3];
                if (Ks < 7) {
                    const int ko = Ks * 32 + quad * 8;
                    a0[0] = *(const bf16x8*)&Fh[fb][ml * FSTR + ko];
                    a0[1] = *(const bf16x8*)&Fl[fb][ml * FSTR + ko];
                    a0[2] = *(const bf16x8*)&Fm[fb][ml * FSTR + ko];
                } else {
                    const int ko = (Ks - 7) * 32 + quad * 8;
                    a0[0] = *(const bf16x8*)&Hh[ml * HSTR + ko];
                    a0[1] = *(const bf16x8*)&Hl[ml * HSTR + ko];
                    a0[2] = *(const bf16x8*)&Hm[ml * HSTR + ko];
                }
                WLOAD(bufB, Wn1, Ks)
                GEMM6(bufA, 0)
                WLOAD(bufA, Wn2, Ks)
                GEMM6(bufB, 1)
                WLOAD(bufB, Wn3, Ks)
                GEMM6(bufA, 2)
                if (Ks < 10) WLOAD(bufA, Wn0, Ks + 1)
                GEMM6(bufB, 3)
            }
        }
#undef WLOAD
#undef GEMM6

        // features for step+1 into the other F buffer (disjoint from GEMM reads)
        if (step + 1 < LL) {
            const int lnext = d ? (LL - 2 - step) : (step + 1);
            DO_FEATURES(lnext, (step + 1) & 1)
        }
        // emissions for step-1 (reads H = h_{step-1}; H not written this phase)
        if (step > 0 && tid < NB * 6) {
            const int lprev = d ? (LL - step) : (step - 1);
            int bb = tid / 6, r6 = tid % 6, t = r6 >> 1, seg = r6 & 1;
            int hb = bb * HSTR + seg * 64;
            const float* wfc = &Wfc_s[t * 128 + seg * 64];
            float s = 0.f;
            #pragma unroll
            for (int i = 0; i < 8; ++i) {
                u16x8 v0 = *(const u16x8*)&Hh[hb + i * 8];
                u16x8 v1 = *(const u16x8*)&Hl[hb + i * 8];
                u16x8 v2 = *(const u16x8*)&Hm[hb + i * 8];
                #pragma unroll
                for (int j = 0; j < 8; ++j) {
                    float h = bf2f(v0[j]) + bf2f(v1[j]) + bf2f(v2[j]);
                    s += h * wfc[i * 8 + j];
                }
            }
            s += __shfl_xor(s, 1);
            if (seg == 0)
                emis[(((b0 + bb) * LL) + lprev) * TT + t] = s;
        }

        __syncthreads();   // all F/H reads done; F[next] writes complete

        // ================= Phase B: gates in-register -> h into H ==========
        #pragma unroll
        for (int nt = 0; nt < 4; ++nt) {
            float zi = acc[nt][0] + bIv[nt];
            float zf = acc[nt][1] + bFv[nt];
            float zg = acc[nt][2] + bGv[nt];
            float zo = acc[nt][3] + bOv[nt];
            float cn = sigm(zf) * cst[nt] + sigm(zi) * tanh_fast(zg);
            cst[nt] = cn;
            float h = sigm(zo) * tanh_fast(cn);
            unsigned short h0 = f2bf(h);
            float r1 = h - bf2f(h0);
            unsigned short h1 = f2bf(r1);
            unsigned short h2 = f2bf(r1 - bf2f(h1));
            int idx = ml * HSTR + un[nt];
            Hh[idx] = h0;
            Hl[idx] = h1;
            Hm[idx] = h2;
        }
        __syncthreads();   // h_step visible for next GEMM / emissions
    }

    // epilogue: emissions for the last step
    if (tid < NB * 6) {
        const int llast = d ? 0 : (LL - 1);
        int bb = tid / 6, r6 = tid % 6, t = r6 >> 1, seg = r6 & 1;
        int hb = bb * HSTR + seg * 64;
        const float* wfc = &Wfc_s[t * 128 + seg * 64];
        float s = 0.f;
        #pragma unroll
        for (int i = 0; i < 8; ++i) {
            u16x8 v0 = *(const u16x8*)&Hh[hb + i * 8];
            u16x8 v1 = *(const u16x8*)&Hl[hb + i * 8];
            u16x8 v2 = *(const u16x8*)&Hm[hb + i * 8];
            #pragma unroll
            for (int j = 0; j < 8; ++j) {
                float h = bf2f(v0[j]) + bf2f(v1[j]) + bf2f(v2[j]);
                s += h * wfc[i * 8 + j];
            }
        }
        s += __shfl_xor(s, 1);
        if (seg == 0)
            emis[(((b0 + bb) * LL) + llast) * TT + t] = s;
    }
#undef DO_FEATURES
}

// ---------------------------------------------------------------------------
// Kernel 3: Viterbi decode. One thread per batch row.
// ---------------------------------------------------------------------------
__global__ void viterbi_kernel(const int* __restrict__ x, const float* __restrict__ ws,
                               const float* __restrict__ trans,
                               const float* __restrict__ start_t,
                               const float* __restrict__ end_t,
                               float* __restrict__ out)
{
    int b = blockIdx.x * blockDim.x + threadIdx.x;
    if (b >= BB) return;
    const float* eF = ws + WS_EMIS;
    const float* eB = ws + WS_EMIS + BB * LL * TT;
    const float eb0 = ws[WS_EB + 0], eb1 = ws[WS_EB + 1], eb2 = ws[WS_EB + 2];
    float tr[9];
    #pragma unroll
    for (int i = 0; i < 9; ++i) tr[i] = trans[i];

    int base = b * LL * TT;
    float s0 = start_t[0] + eF[base + 0] + eB[base + 0] + eb0;
    float s1 = start_t[1] + eF[base + 1] + eB[base + 1] + eb1;
    float s2 = start_t[2] + eF[base + 2] + eB[base + 2] + eb2;

    unsigned hist[LL - 1];
    unsigned maskbits = 0;

    #pragma unroll
    for (int l = 1; l < LL; ++l) {
        bool m = x[(b * LL + l) * WW + 2] > 0;
        if (m) maskbits |= (1u << l);
        int idx = base + l * TT;
        float e0 = eF[idx + 0] + eB[idx + 0] + eb0;
        float e1 = eF[idx + 1] + eB[idx + 1] + eb1;
        float e2 = eF[idx + 2] + eB[idx + 2] + eb2;

        float ns[3]; int pt[3];
        #pragma unroll
        for (int nt = 0; nt < 3; ++nt) {
            float c0 = s0 + tr[0 * 3 + nt];
            float c1 = s1 + tr[1 * 3 + nt];
            float c2 = s2 + tr[2 * 3 + nt];
            int p = 0; float bc = c0;
            if (c1 > bc) { bc = c1; p = 1; }   // strict '>': first-index argmax
            if (c2 > bc) { bc = c2; p = 2; }
            ns[nt] = bc; pt[nt] = p;
        }
        ns[0] += e0; ns[1] += e1; ns[2] += e2;
        hist[l - 1] = (unsigned)pt[0] | ((unsigned)pt[1] << 2) | ((unsigned)pt[2] << 4);
        if (m) { s0 = ns[0]; s1 = ns[1]; s2 = ns[2]; }
    }
    s0 += end_t[0]; s1 += end_t[1]; s2 += end_t[2];
    float best = s0; int last = 0;
    if (s1 > best) { best = s1; last = 1; }
    if (s2 > best) { best = s2; last = 2; }

    out[b] = best;
    float* tags = out + BB + b * LL;
    int tag = last;
    tags[LL - 1] = (float)last;
    #pragma unroll
    for (int l = LL - 1; l >= 1; --l) {
        int prev = (int)((hist[l - 1] >> (2 * tag)) & 3u);
        if (maskbits & (1u << l)) tag = prev;
        tags[l - 1] = (float)tag;
    }
}

// ---------------------------------------------------------------------------
extern "C" void kernel_launch(void* const* d_in, const int* in_sizes, int n_in,
                              void* d_out, int out_size, void* d_ws, size_t ws_size,
                              hipStream_t stream)
{
    const int*   x      = (const int*)  d_in[0];
    const float* emb    = (const float*)d_in[1];
    const float* conv_w = (const float*)d_in[2];
    const float* conv_b = (const float*)d_in[3];
    const float* bn1_g  = (const float*)d_in[4];
    const float* bn1_b  = (const float*)d_in[5];
    const float* bn1_m  = (const float*)d_in[6];
    const float* bn1_v  = (const float*)d_in[7];
    const float* w_ih_f = (const float*)d_in[8];
    const float* w_hh_f = (const float*)d_in[9];
    const float* b_f    = (const float*)d_in[10];
    const float* w_ih_b = (const float*)d_in[11];
    const float* w_hh_b = (const float*)d_in[12];
    const float* b_b    = (const float*)d_in[13];
    const float* bn2_g  = (const float*)d_in[14];
    const float* bn2_b  = (const float*)d_in[15];
    const float* bn2_m  = (const float*)d_in[16];
    const float* bn2_v  = (const float*)d_in[17];
    const float* fc_w   = (const float*)d_in[18];
    const float* fc_b   = (const float*)d_in[19];
    const float* trans  = (const float*)d_in[20];
    const float* start_t= (const float*)d_in[21];
    const float* end_t  = (const float*)d_in[22];

    float* ws  = (float*)d_ws;
    float* out = (float*)d_out;

    prep_kernel<<<256, 256, 0, stream>>>(emb, conv_w, conv_b,
                                         bn1_g, bn1_b, bn1_m, bn1_v,
                                         w_ih_f, w_hh_f, b_f,
                                         w_ih_b, w_hh_b, b_b,
                                         bn2_g, bn2_b, bn2_m, bn2_v,
                                         fc_w, fc_b, ws);
    lstm_kernel<<<512, 512, 0, stream>>>(x, ws);
    viterbi_kernel<<<16, 256, 0, stream>>>(x, ws, trans, start_t, end_t, out);
}

// Round 15
// 811.864 us; speedup vs baseline: 1.4835x; 1.4835x over previous
//
#include <hip/hip_runtime.h>
#include <math.h>

// Problem constants
#define BB    4096   // batch
#define LL    30     // seq len
#define WW    5      // window
#define CC    40     // conv channels
#define HH    128    // lstm units
#define TT    3      // crf tags
#define KA    328    // 200 (features) + 128 (h)
#define NB    32     // batch rows per LSTM block (R13 value — best measured)
#define FSTR  232    // F row stride (u16): 7 K-chunks = 224 cols (200 real + 24 pad)
#define HSTR  136    // H row stride (u16): 128 cols + pad (16B-aligned rows)
#define CW    1056   // per-column W footprint in ushorts: 11 Ks * 3 s * 32 k

// Workspace layout (in floats)
#define WS_P    0                         // P'[3][30][40] conv collapsed + bn1 folded
#define WS_BC   3600                      // biasC[40]
#define WS_BG   3648                      // biasG[2][512]
#define WS_WFC  4672                      // Wfc[2][3][128]  (fc folded with bn2)
#define WS_EB   5440                      // ebias[3]
#define WS_WBF  5504                      // bf16 W [d][n][Ks][s][32]: 540672 floats
#define WS_EMIS (5504 + 540672)           // emis[2][B][L][3] partial emissions

typedef __bf16 bf16x8 __attribute__((ext_vector_type(8)));
typedef float  f32x4  __attribute__((ext_vector_type(4)));
typedef unsigned short u16x8 __attribute__((ext_vector_type(8)));

__device__ __forceinline__ float sigm(float x) {
    return __builtin_amdgcn_rcpf(1.0f + __expf(-x));
}
__device__ __forceinline__ float tanh_fast(float x) {
    return 2.0f * __builtin_amdgcn_rcpf(1.0f + __expf(-2.0f * x)) - 1.0f;
}
// bf16 round-to-nearest-even helpers
__device__ __forceinline__ unsigned short f2bf(float f) {
    unsigned u = __builtin_bit_cast(unsigned, f);
    return (unsigned short)((u + 0x7FFFu + ((u >> 16) & 1u)) >> 16);
}
__device__ __forceinline__ float bf2f(unsigned short h) {
    unsigned u = ((unsigned)h) << 16;
    return __builtin_bit_cast(float, u);
}

// ---------------------------------------------------------------------------
// Kernel 1: fold BN1 into conv tables, 3-term split-bf16 repack of LSTM
// weights ([d][n][Ks][s][32] — per-column offsets are load immediates),
// fold BN2 into FC. W k-map matches A-side: k<200 wih; 200..223 zero (F pad);
// 224..351 whh[k-224].  (unchanged from R13)
// ---------------------------------------------------------------------------
__global__ void prep_kernel(const float* __restrict__ emb, const float* __restrict__ conv_w,
                            const float* __restrict__ conv_b,
                            const float* __restrict__ bn1_g, const float* __restrict__ bn1_b,
                            const float* __restrict__ bn1_m, const float* __restrict__ bn1_v,
                            const float* __restrict__ w_ih_f, const float* __restrict__ w_hh_f,
                            const float* __restrict__ b_f,
                            const float* __restrict__ w_ih_b, const float* __restrict__ w_hh_b,
                            const float* __restrict__ b_b,
                            const float* __restrict__ bn2_g, const float* __restrict__ bn2_b,
                            const float* __restrict__ bn2_m, const float* __restrict__ bn2_v,
                            const float* __restrict__ fc_w, const float* __restrict__ fc_b,
                            float* __restrict__ ws)
{
    const int gid = blockIdx.x * blockDim.x + threadIdx.x;
    const int gsz = gridDim.x * blockDim.x;

    for (int idx = gid; idx < 3600; idx += gsz) {
        int k = idx / 1200, rem = idx % 1200, a = rem / 40, c = rem % 40;
        float s1 = bn1_g[c] / sqrtf(bn1_v[c] + 1e-5f);
        float acc = 0.f;
        for (int e = 0; e < 128; ++e)
            acc += emb[a * 128 + e] * conv_w[(c * 128 + e) * 3 + k];
        ws[WS_P + idx] = acc * s1;
    }
    for (int c = gid; c < CC; c += gsz) {
        float s1 = bn1_g[c] / sqrtf(bn1_v[c] + 1e-5f);
        ws[WS_BC + c] = (conv_b[c] - bn1_m[c]) * s1 + bn1_b[c];
    }
    for (int i = gid; i < 1024; i += gsz) {
        int d = i >> 9, g = i & 511;
        ws[WS_BG + i] = d ? b_b[g] : b_f[g];
    }
    for (int i = gid; i < 768; i += gsz) {
        int d = i / 384, r = i % 384, t = r / 128, u = r % 128;
        int j = d * 128 + u;
        float s2 = bn2_g[j] / sqrtf(bn2_v[j] + 1e-5f);
        ws[WS_WFC + i] = fc_w[t * 256 + j] * s2;
    }
    for (int t = gid; t < TT; t += gsz) {
        float acc = fc_b[t];
        for (int j = 0; j < 256; ++j) {
            float s2 = bn2_g[j] / sqrtf(bn2_v[j] + 1e-5f);
            acc += fc_w[t * 256 + j] * (bn2_b[j] - bn2_m[j] * s2);
        }
        ws[WS_EB + t] = acc;
    }
    // Wbf[d][n][Ks][s][32]: n = 4u+g; per column all Ks/s chunks contiguous.
    unsigned short* wsu = (unsigned short*)ws;
    for (int i = gid; i < 2 * 512 * CW; i += gsz) {
        int d = i / (512 * CW), r = i % (512 * CW);
        int n = r / CW, q = r % CW;
        int Ks = q / 96, t = q % 96, s = t / 32, k32 = t % 32;
        int k = Ks * 32 + k32;
        int u = n >> 2, g = n & 3, row = g * 128 + u;
        const float* wih = d ? w_ih_b : w_ih_f;
        const float* whh = d ? w_hh_b : w_hh_f;
        float w = (k < 200) ? wih[row * 200 + k]
                            : ((k >= 224) ? whh[row * 128 + (k - 224)] : 0.f);
        unsigned short t0 = f2bf(w);
        float r1 = w - bf2f(t0);
        unsigned short t1 = f2bf(r1);
        unsigned short t2 = f2bf(r1 - bf2f(t1));
        wsu[2 * WS_WBF + i] = (s == 0) ? t0 : ((s == 1) ? t1 : t2);
    }
}

// ---------------------------------------------------------------------------
// Kernel 2: fused features + BiLSTM (3-term split-bf16 MFMA) + emissions.
// R15 = R13 structure (NB=32, 1 block/CU, 2 barriers/step) with the W
// pipeline deepened to a FULL Ks iteration: wbuf[2][4][3] double buffer,
// all 12 next-Ks loads issued before the current Ks's 48 mfma (~230-470 cyc
// of cover vs ~200 cyc L2 latency). R13's 1-slot prefetch (29-58 cyc) left
// the K-loop latency-exposed (R14's NB=16 made it worse: 19.8% MfmaUtil).
// Numerics identical to R9-R13 (6 products, same order).
// ---------------------------------------------------------------------------
__global__ __launch_bounds__(512, 1)
void lstm_kernel(const int* __restrict__ x, float* __restrict__ ws)
{
    __shared__ unsigned short Fh[2][NB * FSTR], Fl[2][NB * FSTR], Fm[2][NB * FSTR];
    __shared__ unsigned short Hh[NB * HSTR], Hl[NB * HSTR], Hm[NB * HSTR];
    __shared__ float Pp_s[3600];
    __shared__ float Wfc_s[384];
    __shared__ float biasC_s[40];

    const int tid = threadIdx.x;
    const int d   = blockIdx.x & 1;
    const int b0  = (blockIdx.x >> 1) * NB;

    const unsigned short* __restrict__ Wb =
        (const unsigned short*)ws + 2 * WS_WBF + d * (512 * CW);
    float* emis = ws + WS_EMIS + d * (BB * LL * TT);

    for (int i = tid; i < 3600; i += 512) Pp_s[i] = ws[WS_P + i];
    for (int i = tid; i < 384;  i += 512) Wfc_s[i] = ws[WS_WFC + d * 384 + i];
    for (int i = tid; i < 40;   i += 512) biasC_s[i] = ws[WS_BC + i];
    // zero F (both buffers; covers K pads) and H (initial h=0)
    for (int i = tid; i < NB * FSTR; i += 512) {
        ((unsigned*)Fh)[i] = 0u; ((unsigned*)Fl)[i] = 0u; ((unsigned*)Fm)[i] = 0u;
    }
    for (int i = tid; i < NB * HSTR / 2; i += 512) {
        ((unsigned*)Hh)[i] = 0u; ((unsigned*)Hl)[i] = 0u; ((unsigned*)Hm)[i] = 0u;
    }

    const int lane = tid & 63;
    const int wv   = tid >> 6;          // 0..7: N-tile group (gate-cols 64*wv..)
    const int quad = lane >> 4;
    const int ml   = lane & 15;

    // 4 W base pointers, one per nt; all further offsets are immediates.
    const unsigned short* __restrict__ Wn[4] = {
        Wb + (wv * 64 +  0 + ml) * CW + quad * 8,
        Wb + (wv * 64 + 16 + ml) * CW + quad * 8,
        Wb + (wv * 64 + 32 + ml) * CW + quad * 8,
        Wb + (wv * 64 + 48 + ml) * CW + quad * 8
    };

    // this lane's units (one per nt) and their gate biases
    const float* bgp = ws + WS_BG + d * 512;
    int   un[4];
    float bIv[4], bFv[4], bGv[4], bOv[4];
    #pragma unroll
    for (int nt = 0; nt < 4; ++nt) {
        int u = wv * 16 + nt * 4 + quad;
        un[nt]  = u;
        bIv[nt] = bgp[u];
        bFv[nt] = bgp[128 + u];
        bGv[nt] = bgp[256 + u];
        bOv[nt] = bgp[384 + u];
    }

    float cst[2][4];
    #pragma unroll
    for (int mt = 0; mt < 2; ++mt)
        #pragma unroll
        for (int nt = 0; nt < 4; ++nt) cst[mt][nt] = 0.f;

    __syncthreads();

    // ---- feature computation into F buffer `buf` for seq position l ----
#define DO_FEATURES(LPOS, BUF)                                                 \
    for (int p = tid; p < NB * CC; p += 512) {                                 \
        int bb = p / CC, c = p % CC;                                           \
        const int* tok = x + (((b0 + bb) * LL) + (LPOS)) * WW;                 \
        int t0 = tok[0], t1 = tok[1], t2 = tok[2], t3 = tok[3], t4 = tok[4];   \
        float bc = biasC_s[c];                                                 \
        float a0 = bc + Pp_s[(30 + t0) * 40 + c] + Pp_s[(60 + t1) * 40 + c];   \
        float a1 = bc + Pp_s[t0 * 40 + c] + Pp_s[(30 + t1) * 40 + c] + Pp_s[(60 + t2) * 40 + c]; \
        float a2 = bc + Pp_s[t1 * 40 + c] + Pp_s[(30 + t2) * 40 + c] + Pp_s[(60 + t3) * 40 + c]; \
        float a3 = bc + Pp_s[t2 * 40 + c] + Pp_s[(30 + t3) * 40 + c] + Pp_s[(60 + t4) * 40 + c]; \
        float a4 = bc + Pp_s[t3 * 40 + c] + Pp_s[(30 + t4) * 40 + c];          \
        a0 = fmaxf(a0, 0.f); a1 = fmaxf(a1, 0.f); a2 = fmaxf(a2, 0.f);         \
        a3 = fmaxf(a3, 0.f); a4 = fmaxf(a4, 0.f);                              \
        float f[5];                                                            \
        f[0] = fmaxf(a0, a1);                                                  \
        f[1] = fmaxf(fmaxf(a0, a1), a2);                                       \
        f[2] = fmaxf(fmaxf(a1, a2), a3);                                       \
        f[3] = fmaxf(fmaxf(a2, a3), a4);                                       \
        f[4] = fmaxf(a3, a4);                                                  \
        int base = bb * FSTR + c * 5;                                          \
        _Pragma("unroll")                                                      \
        for (int j = 0; j < 5; ++j) {                                          \
            unsigned short h0 = f2bf(f[j]);                                    \
            float r1 = f[j] - bf2f(h0);                                        \
            unsigned short h1 = f2bf(r1);                                      \
            unsigned short h2 = f2bf(r1 - bf2f(h1));                           \
            Fh[BUF][base + j] = h0;                                            \
            Fl[BUF][base + j] = h1;                                            \
            Fm[BUF][base + j] = h2;                                            \
        }                                                                      \
    }

    // prologue: features for step 0
    {
        const int l0 = d ? (LL - 1) : 0;
        DO_FEATURES(l0, 0)
    }
    __syncthreads();

    for (int step = 0; step < LL; ++step) {
        const int fb = step & 1;

        // ================= Phase A: GEMM + features(t+1) + emissions(t-1) ==
        f32x4 acc[2][4];
        #pragma unroll
        for (int mt = 0; mt < 2; ++mt)
            #pragma unroll
            for (int nt = 0; nt < 4; ++nt)
                acc[mt][nt] = (f32x4){0.f, 0.f, 0.f, 0.f};

#define WLOAD(B, P, KS)                                                        \
        {                                                                      \
            B[0] = *(const bf16x8*)((P) + (KS) * 96);                          \
            B[1] = *(const bf16x8*)((P) + (KS) * 96 + 32);                     \
            B[2] = *(const bf16x8*)((P) + (KS) * 96 + 64);                     \
        }
        // D = W' * A'  (same 6 products, same order as R9-R13)
#define GEMM6(B, NT)                                                           \
        {                                                                      \
            acc[0][NT] = __builtin_amdgcn_mfma_f32_16x16x32_bf16(B[0], a0[0], acc[0][NT], 0, 0, 0); \
            acc[0][NT] = __builtin_amdgcn_mfma_f32_16x16x32_bf16(B[0], a0[1], acc[0][NT], 0, 0, 0); \
            acc[0][NT] = __builtin_amdgcn_mfma_f32_16x16x32_bf16(B[1], a0[0], acc[0][NT], 0, 0, 0); \
            acc[0][NT] = __builtin_amdgcn_mfma_f32_16x16x32_bf16(B[1], a0[1], acc[0][NT], 0, 0, 0); \
            acc[0][NT] = __builtin_amdgcn_mfma_f32_16x16x32_bf16(B[2], a0[0], acc[0][NT], 0, 0, 0); \
            acc[0][NT] = __builtin_amdgcn_mfma_f32_16x16x32_bf16(B[0], a0[2], acc[0][NT], 0, 0, 0); \
            acc[1][NT] = __builtin_amdgcn_mfma_f32_16x16x32_bf16(B[0], a1[0], acc[1][NT], 0, 0, 0); \
            acc[1][NT] = __builtin_amdgcn_mfma_f32_16x16x32_bf16(B[0], a1[1], acc[1][NT], 0, 0, 0); \
            acc[1][NT] = __builtin_amdgcn_mfma_f32_16x16x32_bf16(B[1], a1[0], acc[1][NT], 0, 0, 0); \
            acc[1][NT] = __builtin_amdgcn_mfma_f32_16x16x32_bf16(B[1], a1[1], acc[1][NT], 0, 0, 0); \
            acc[1][NT] = __builtin_amdgcn_mfma_f32_16x16x32_bf16(B[2], a1[0], acc[1][NT], 0, 0, 0); \
            acc[1][NT] = __builtin_amdgcn_mfma_f32_16x16x32_bf16(B[0], a1[2], acc[1][NT], 0, 0, 0); \
        }

        {
            // deep pipeline: full-Ks double buffer (12 loads in flight)
            bf16x8 wbuf[2][4][3];
            #pragma unroll
            for (int nt = 0; nt < 4; ++nt)
                WLOAD(wbuf[0][nt], Wn[nt], 0)

            #pragma unroll
            for (int Ks = 0; Ks < 11; ++Ks) {
                const int cur = Ks & 1, nxt = cur ^ 1;
                // issue ALL next-Ks W loads before touching current buffers
                if (Ks < 10) {
                    #pragma unroll
                    for (int nt = 0; nt < 4; ++nt)
                        WLOAD(wbuf[nxt][nt], Wn[nt], Ks + 1)
                }
                bf16x8 a0[3], a1[3];
                if (Ks < 7) {
                    const int ko = Ks * 32 + quad * 8;
                    a0[0] = *(const bf16x8*)&Fh[fb][ml * FSTR + ko];
                    a0[1] = *(const bf16x8*)&Fl[fb][ml * FSTR + ko];
                    a0[2] = *(const bf16x8*)&Fm[fb][ml * FSTR + ko];
                    a1[0] = *(const bf16x8*)&Fh[fb][(16 + ml) * FSTR + ko];
                    a1[1] = *(const bf16x8*)&Fl[fb][(16 + ml) * FSTR + ko];
                    a1[2] = *(const bf16x8*)&Fm[fb][(16 + ml) * FSTR + ko];
                } else {
                    const int ko = (Ks - 7) * 32 + quad * 8;
                    a0[0] = *(const bf16x8*)&Hh[ml * HSTR + ko];
                    a0[1] = *(const bf16x8*)&Hl[ml * HSTR + ko];
                    a0[2] = *(const bf16x8*)&Hm[ml * HSTR + ko];
                    a1[0] = *(const bf16x8*)&Hh[(16 + ml) * HSTR + ko];
                    a1[1] = *(const bf16x8*)&Hl[(16 + ml) * HSTR + ko];
                    a1[2] = *(const bf16x8*)&Hm[(16 + ml) * HSTR + ko];
                }
                GEMM6(wbuf[cur][0], 0)
                GEMM6(wbuf[cur][1], 1)
                GEMM6(wbuf[cur][2], 2)
                GEMM6(wbuf[cur][3], 3)
            }
        }
#undef WLOAD
#undef GEMM6

        // features for step+1 into the other F buffer (disjoint from GEMM reads)
        if (step + 1 < LL) {
            const int lnext = d ? (LL - 2 - step) : (step + 1);
            DO_FEATURES(lnext, (step + 1) & 1)
        }
        // emissions for step-1 (reads H = h_{step-1}; H not written this phase)
        if (step > 0 && tid < 192) {
            const int lprev = d ? (LL - step) : (step - 1);
            int bb = tid / 6, r6 = tid % 6, t = r6 >> 1, seg = r6 & 1;
            int hb = bb * HSTR + seg * 64;
            const float* wfc = &Wfc_s[t * 128 + seg * 64];
            float s = 0.f;
            #pragma unroll
            for (int i = 0; i < 8; ++i) {
                u16x8 v0 = *(const u16x8*)&Hh[hb + i * 8];
                u16x8 v1 = *(const u16x8*)&Hl[hb + i * 8];
                u16x8 v2 = *(const u16x8*)&Hm[hb + i * 8];
                #pragma unroll
                for (int j = 0; j < 8; ++j) {
                    float h = bf2f(v0[j]) + bf2f(v1[j]) + bf2f(v2[j]);
                    s += h * wfc[i * 8 + j];
                }
            }
            s += __shfl_xor(s, 1);
            if (seg == 0)
                emis[(((b0 + bb) * LL) + lprev) * TT + t] = s;
        }

        __syncthreads();   // all F/H reads done; F[next] writes complete

        // ================= Phase B: gates in-register -> h into H ==========
        #pragma unroll
        for (int mt = 0; mt < 2; ++mt) {
            #pragma unroll
            for (int nt = 0; nt < 4; ++nt) {
                float zi = acc[mt][nt][0] + bIv[nt];
                float zf = acc[mt][nt][1] + bFv[nt];
                float zg = acc[mt][nt][2] + bGv[nt];
                float zo = acc[mt][nt][3] + bOv[nt];
                float cn = sigm(zf) * cst[mt][nt] + sigm(zi) * tanh_fast(zg);
                cst[mt][nt] = cn;
                float h = sigm(zo) * tanh_fast(cn);
                unsigned short h0 = f2bf(h);
                float r1 = h - bf2f(h0);
                unsigned short h1 = f2bf(r1);
                unsigned short h2 = f2bf(r1 - bf2f(h1));
                int idx = (mt * 16 + ml) * HSTR + un[nt];
                Hh[idx] = h0;
                Hl[idx] = h1;
                Hm[idx] = h2;
            }
        }
        __syncthreads();   // h_step visible for next GEMM / emissions
    }

    // epilogue: emissions for the last step
    if (tid < 192) {
        const int llast = d ? 0 : (LL - 1);
        int bb = tid / 6, r6 = tid % 6, t = r6 >> 1, seg = r6 & 1;
        int hb = bb * HSTR + seg * 64;
        const float* wfc = &Wfc_s[t * 128 + seg * 64];
        float s = 0.f;
        #pragma unroll
        for (int i = 0; i < 8; ++i) {
            u16x8 v0 = *(const u16x8*)&Hh[hb + i * 8];
            u16x8 v1 = *(const u16x8*)&Hl[hb + i * 8];
            u16x8 v2 = *(const u16x8*)&Hm[hb + i * 8];
            #pragma unroll
            for (int j = 0; j < 8; ++j) {
                float h = bf2f(v0[j]) + bf2f(v1[j]) + bf2f(v2[j]);
                s += h * wfc[i * 8 + j];
            }
        }
        s += __shfl_xor(s, 1);
        if (seg == 0)
            emis[(((b0 + bb) * LL) + llast) * TT + t] = s;
    }
#undef DO_FEATURES
}

// ---------------------------------------------------------------------------
// Kernel 3: Viterbi decode. One thread per batch row.
// ---------------------------------------------------------------------------
__global__ void viterbi_kernel(const int* __restrict__ x, const float* __restrict__ ws,
                               const float* __restrict__ trans,
                               const float* __restrict__ start_t,
                               const float* __restrict__ end_t,
                               float* __restrict__ out)
{
    int b = blockIdx.x * blockDim.x + threadIdx.x;
    if (b >= BB) return;
    const float* eF = ws + WS_EMIS;
    const float* eB = ws + WS_EMIS + BB * LL * TT;
    const float eb0 = ws[WS_EB + 0], eb1 = ws[WS_EB + 1], eb2 = ws[WS_EB + 2];
    float tr[9];
    #pragma unroll
    for (int i = 0; i < 9; ++i) tr[i] = trans[i];

    int base = b * LL * TT;
    float s0 = start_t[0] + eF[base + 0] + eB[base + 0] + eb0;
    float s1 = start_t[1] + eF[base + 1] + eB[base + 1] + eb1;
    float s2 = start_t[2] + eF[base + 2] + eB[base + 2] + eb2;

    unsigned hist[LL - 1];
    unsigned maskbits = 0;

    #pragma unroll
    for (int l = 1; l < LL; ++l) {
        bool m = x[(b * LL + l) * WW + 2] > 0;
        if (m) maskbits |= (1u << l);
        int idx = base + l * TT;
        float e0 = eF[idx + 0] + eB[idx + 0] + eb0;
        float e1 = eF[idx + 1] + eB[idx + 1] + eb1;
        float e2 = eF[idx + 2] + eB[idx + 2] + eb2;

        float ns[3]; int pt[3];
        #pragma unroll
        for (int nt = 0; nt < 3; ++nt) {
            float c0 = s0 + tr[0 * 3 + nt];
            float c1 = s1 + tr[1 * 3 + nt];
            float c2 = s2 + tr[2 * 3 + nt];
            int p = 0; float bc = c0;
            if (c1 > bc) { bc = c1; p = 1; }   // strict '>': first-index argmax
            if (c2 > bc) { bc = c2; p = 2; }
            ns[nt] = bc; pt[nt] = p;
        }
        ns[0] += e0; ns[1] += e1; ns[2] += e2;
        hist[l - 1] = (unsigned)pt[0] | ((unsigned)pt[1] << 2) | ((unsigned)pt[2] << 4);
        if (m) { s0 = ns[0]; s1 = ns[1]; s2 = ns[2]; }
    }
    s0 += end_t[0]; s1 += end_t[1]; s2 += end_t[2];
    float best = s0; int last = 0;
    if (s1 > best) { best = s1; last = 1; }
    if (s2 > best) { best = s2; last = 2; }

    out[b] = best;
    float* tags = out + BB + b * LL;
    int tag = last;
    tags[LL - 1] = (float)last;
    #pragma unroll
    for (int l = LL - 1; l >= 1; --l) {
        int prev = (int)((hist[l - 1] >> (2 * tag)) & 3u);
        if (maskbits & (1u << l)) tag = prev;
        tags[l - 1] = (float)tag;
    }
}

// ---------------------------------------------------------------------------
extern "C" void kernel_launch(void* const* d_in, const int* in_sizes, int n_in,
                              void* d_out, int out_size, void* d_ws, size_t ws_size,
                              hipStream_t stream)
{
    const int*   x      = (const int*)  d_in[0];
    const float* emb    = (const float*)d_in[1];
    const float* conv_w = (const float*)d_in[2];
    const float* conv_b = (const float*)d_in[3];
    const float* bn1_g  = (const float*)d_in[4];
    const float* bn1_b  = (const float*)d_in[5];
    const float* bn1_m  = (const float*)d_in[6];
    const float* bn1_v  = (const float*)d_in[7];
    const float* w_ih_f = (const float*)d_in[8];
    const float* w_hh_f = (const float*)d_in[9];
    const float* b_f    = (const float*)d_in[10];
    const float* w_ih_b = (const float*)d_in[11];
    const float* w_hh_b = (const float*)d_in[12];
    const float* b_b    = (const float*)d_in[13];
    const float* bn2_g  = (const float*)d_in[14];
    const float* bn2_b  = (const float*)d_in[15];
    const float* bn2_m  = (const float*)d_in[16];
    const float* bn2_v  = (const float*)d_in[17];
    const float* fc_w   = (const float*)d_in[18];
    const float* fc_b   = (const float*)d_in[19];
    const float* trans  = (const float*)d_in[20];
    const float* start_t= (const float*)d_in[21];
    const float* end_t  = (const float*)d_in[22];

    float* ws  = (float*)d_ws;
    float* out = (float*)d_out;

    prep_kernel<<<256, 256, 0, stream>>>(emb, conv_w, conv_b,
                                         bn1_g, bn1_b, bn1_m, bn1_v,
                                         w_ih_f, w_hh_f, b_f,
                                         w_ih_b, w_hh_b, b_b,
                                         bn2_g, bn2_b, bn2_m, bn2_v,
                                         fc_w, fc_b, ws);
    lstm_kernel<<<256, 512, 0, stream>>>(x, ws);
    viterbi_kernel<<<16, 256, 0, stream>>>(x, ws, trans, start_t, end_t, out);
}

// Round 16
// 762.875 us; speedup vs baseline: 1.5788x; 1.0642x over previous
//
#include <hip/hip_runtime.h>
#include <math.h>

// Problem constants
#define BB    4096   // batch
#define LL    30     // seq len
#define WW    5      // window
#define CC    40     // conv channels
#define HH    128    // lstm units
#define TT    3      // crf tags
#define KA    328    // 200 (features) + 128 (h)
#define NB    32     // batch rows per LSTM block
#define NT_   1024   // threads per block (R16: 16 waves -> 4 waves/SIMD)
#define FSTR  232    // F row stride (u16): 7 K-chunks = 224 cols (200 real + 24 pad)
#define HSTR  136    // H row stride (u16): 128 cols + pad (16B-aligned rows)
#define CW    1056   // per-column W footprint in ushorts: 11 Ks * 3 s * 32 k

// Workspace layout (in floats)
#define WS_P    0                         // P'[3][30][40] conv collapsed + bn1 folded
#define WS_BC   3600                      // biasC[40]
#define WS_BG   3648                      // biasG[2][512]
#define WS_WFC  4672                      // Wfc[2][3][128]  (fc folded with bn2)
#define WS_EB   5440                      // ebias[3]
#define WS_WBF  5504                      // bf16 W [d][n][Ks][s][32]: 540672 floats
#define WS_EMIS (5504 + 540672)           // emis[2][B][L][3] partial emissions

typedef __bf16 bf16x8 __attribute__((ext_vector_type(8)));
typedef float  f32x4  __attribute__((ext_vector_type(4)));
typedef unsigned short u16x8 __attribute__((ext_vector_type(8)));

__device__ __forceinline__ float sigm(float x) {
    return __builtin_amdgcn_rcpf(1.0f + __expf(-x));
}
__device__ __forceinline__ float tanh_fast(float x) {
    return 2.0f * __builtin_amdgcn_rcpf(1.0f + __expf(-2.0f * x)) - 1.0f;
}
// bf16 round-to-nearest-even helpers
__device__ __forceinline__ unsigned short f2bf(float f) {
    unsigned u = __builtin_bit_cast(unsigned, f);
    return (unsigned short)((u + 0x7FFFu + ((u >> 16) & 1u)) >> 16);
}
__device__ __forceinline__ float bf2f(unsigned short h) {
    unsigned u = ((unsigned)h) << 16;
    return __builtin_bit_cast(float, u);
}

// ---------------------------------------------------------------------------
// Kernel 1: fold BN1 into conv tables, 3-term split-bf16 repack of LSTM
// weights ([d][n][Ks][s][32] — per-column offsets are load immediates),
// fold BN2 into FC. W k-map matches A-side: k<200 wih; 200..223 zero (F pad);
// 224..351 whh[k-224].  (unchanged from R13)
// ---------------------------------------------------------------------------
__global__ void prep_kernel(const float* __restrict__ emb, const float* __restrict__ conv_w,
                            const float* __restrict__ conv_b,
                            const float* __restrict__ bn1_g, const float* __restrict__ bn1_b,
                            const float* __restrict__ bn1_m, const float* __restrict__ bn1_v,
                            const float* __restrict__ w_ih_f, const float* __restrict__ w_hh_f,
                            const float* __restrict__ b_f,
                            const float* __restrict__ w_ih_b, const float* __restrict__ w_hh_b,
                            const float* __restrict__ b_b,
                            const float* __restrict__ bn2_g, const float* __restrict__ bn2_b,
                            const float* __restrict__ bn2_m, const float* __restrict__ bn2_v,
                            const float* __restrict__ fc_w, const float* __restrict__ fc_b,
                            float* __restrict__ ws)
{
    const int gid = blockIdx.x * blockDim.x + threadIdx.x;
    const int gsz = gridDim.x * blockDim.x;

    for (int idx = gid; idx < 3600; idx += gsz) {
        int k = idx / 1200, rem = idx % 1200, a = rem / 40, c = rem % 40;
        float s1 = bn1_g[c] / sqrtf(bn1_v[c] + 1e-5f);
        float acc = 0.f;
        for (int e = 0; e < 128; ++e)
            acc += emb[a * 128 + e] * conv_w[(c * 128 + e) * 3 + k];
        ws[WS_P + idx] = acc * s1;
    }
    for (int c = gid; c < CC; c += gsz) {
        float s1 = bn1_g[c] / sqrtf(bn1_v[c] + 1e-5f);
        ws[WS_BC + c] = (conv_b[c] - bn1_m[c]) * s1 + bn1_b[c];
    }
    for (int i = gid; i < 1024; i += gsz) {
        int d = i >> 9, g = i & 511;
        ws[WS_BG + i] = d ? b_b[g] : b_f[g];
    }
    for (int i = gid; i < 768; i += gsz) {
        int d = i / 384, r = i % 384, t = r / 128, u = r % 128;
        int j = d * 128 + u;
        float s2 = bn2_g[j] / sqrtf(bn2_v[j] + 1e-5f);
        ws[WS_WFC + i] = fc_w[t * 256 + j] * s2;
    }
    for (int t = gid; t < TT; t += gsz) {
        float acc = fc_b[t];
        for (int j = 0; j < 256; ++j) {
            float s2 = bn2_g[j] / sqrtf(bn2_v[j] + 1e-5f);
            acc += fc_w[t * 256 + j] * (bn2_b[j] - bn2_m[j] * s2);
        }
        ws[WS_EB + t] = acc;
    }
    // Wbf[d][n][Ks][s][32]: n = 4u+g; per column all Ks/s chunks contiguous.
    unsigned short* wsu = (unsigned short*)ws;
    for (int i = gid; i < 2 * 512 * CW; i += gsz) {
        int d = i / (512 * CW), r = i % (512 * CW);
        int n = r / CW, q = r % CW;
        int Ks = q / 96, t = q % 96, s = t / 32, k32 = t % 32;
        int k = Ks * 32 + k32;
        int u = n >> 2, g = n & 3, row = g * 128 + u;
        const float* wih = d ? w_ih_b : w_ih_f;
        const float* whh = d ? w_hh_b : w_hh_f;
        float w = (k < 200) ? wih[row * 200 + k]
                            : ((k >= 224) ? whh[row * 128 + (k - 224)] : 0.f);
        unsigned short t0 = f2bf(w);
        float r1 = w - bf2f(t0);
        unsigned short t1 = f2bf(r1);
        unsigned short t2 = f2bf(r1 - bf2f(t1));
        wsu[2 * WS_WBF + i] = (s == 0) ? t0 : ((s == 1) ? t1 : t2);
    }
}

// ---------------------------------------------------------------------------
// Kernel 2: fused features + BiLSTM (3-term split-bf16 MFMA) + emissions.
// R16: 1024 threads/block (16 waves = 4 waves/SIMD), 1 block/CU, NB=32.
// Each wave owns 32 gate-cols (2 nt-tiles of 16): W traffic per CU unchanged
// vs R13 (each col loaded once/block), mfma density per W-load group
// unchanged (12), but TLP doubles — waves in different phase positions
// overlap MFMA with features/gates VALU. Each 16-col MFMA tile runs the
// identical 6-product sequence -> bitwise-identical numerics to R9-R15.
// ---------------------------------------------------------------------------
__global__ __launch_bounds__(1024, 1)
void lstm_kernel(const int* __restrict__ x, float* __restrict__ ws)
{
    __shared__ unsigned short Fh[2][NB * FSTR], Fl[2][NB * FSTR], Fm[2][NB * FSTR];
    __shared__ unsigned short Hh[NB * HSTR], Hl[NB * HSTR], Hm[NB * HSTR];
    __shared__ float Pp_s[3600];
    __shared__ float Wfc_s[384];
    __shared__ float biasC_s[40];

    const int tid = threadIdx.x;
    const int d   = blockIdx.x & 1;
    const int b0  = (blockIdx.x >> 1) * NB;

    const unsigned short* __restrict__ Wb =
        (const unsigned short*)ws + 2 * WS_WBF + d * (512 * CW);
    float* emis = ws + WS_EMIS + d * (BB * LL * TT);

    for (int i = tid; i < 3600; i += NT_) Pp_s[i] = ws[WS_P + i];
    for (int i = tid; i < 384;  i += NT_) Wfc_s[i] = ws[WS_WFC + d * 384 + i];
    for (int i = tid; i < 40;   i += NT_) biasC_s[i] = ws[WS_BC + i];
    // zero F (both buffers; covers K pads) and H (initial h=0)
    for (int i = tid; i < NB * FSTR; i += NT_) {
        ((unsigned*)Fh)[i] = 0u; ((unsigned*)Fl)[i] = 0u; ((unsigned*)Fm)[i] = 0u;
    }
    for (int i = tid; i < NB * HSTR / 2; i += NT_) {
        ((unsigned*)Hh)[i] = 0u; ((unsigned*)Hl)[i] = 0u; ((unsigned*)Hm)[i] = 0u;
    }

    const int lane = tid & 63;
    const int wv   = tid >> 6;          // 0..15: N-tile group (gate-cols 32*wv..)
    const int quad = lane >> 4;
    const int ml   = lane & 15;

    // 2 W base pointers, one per nt; all further offsets are immediates.
    const unsigned short* __restrict__ Wn[2] = {
        Wb + (wv * 32 +  0 + ml) * CW + quad * 8,
        Wb + (wv * 32 + 16 + ml) * CW + quad * 8
    };

    // this lane's units (one per nt) and their gate biases
    const float* bgp = ws + WS_BG + d * 512;
    int   un[2];
    float bIv[2], bFv[2], bGv[2], bOv[2];
    #pragma unroll
    for (int nt = 0; nt < 2; ++nt) {
        int u = wv * 8 + nt * 4 + quad;
        un[nt]  = u;
        bIv[nt] = bgp[u];
        bFv[nt] = bgp[128 + u];
        bGv[nt] = bgp[256 + u];
        bOv[nt] = bgp[384 + u];
    }

    float cst[2][2];
    #pragma unroll
    for (int mt = 0; mt < 2; ++mt)
        #pragma unroll
        for (int nt = 0; nt < 2; ++nt) cst[mt][nt] = 0.f;

    __syncthreads();

    // ---- feature computation into F buffer `buf` for seq position l ----
#define DO_FEATURES(LPOS, BUF)                                                 \
    for (int p = tid; p < NB * CC; p += NT_) {                                 \
        int bb = p / CC, c = p % CC;                                           \
        const int* tok = x + (((b0 + bb) * LL) + (LPOS)) * WW;                 \
        int t0 = tok[0], t1 = tok[1], t2 = tok[2], t3 = tok[3], t4 = tok[4];   \
        float bc = biasC_s[c];                                                 \
        float a0 = bc + Pp_s[(30 + t0) * 40 + c] + Pp_s[(60 + t1) * 40 + c];   \
        float a1 = bc + Pp_s[t0 * 40 + c] + Pp_s[(30 + t1) * 40 + c] + Pp_s[(60 + t2) * 40 + c]; \
        float a2 = bc + Pp_s[t1 * 40 + c] + Pp_s[(30 + t2) * 40 + c] + Pp_s[(60 + t3) * 40 + c]; \
        float a3 = bc + Pp_s[t2 * 40 + c] + Pp_s[(30 + t3) * 40 + c] + Pp_s[(60 + t4) * 40 + c]; \
        float a4 = bc + Pp_s[t3 * 40 + c] + Pp_s[(30 + t4) * 40 + c];          \
        a0 = fmaxf(a0, 0.f); a1 = fmaxf(a1, 0.f); a2 = fmaxf(a2, 0.f);         \
        a3 = fmaxf(a3, 0.f); a4 = fmaxf(a4, 0.f);                              \
        float f[5];                                                            \
        f[0] = fmaxf(a0, a1);                                                  \
        f[1] = fmaxf(fmaxf(a0, a1), a2);                                       \
        f[2] = fmaxf(fmaxf(a1, a2), a3);                                       \
        f[3] = fmaxf(fmaxf(a2, a3), a4);                                       \
        f[4] = fmaxf(a3, a4);                                                  \
        int base = bb * FSTR + c * 5;                                          \
        _Pragma("unroll")                                                      \
        for (int j = 0; j < 5; ++j) {                                          \
            unsigned short h0 = f2bf(f[j]);                                    \
            float r1 = f[j] - bf2f(h0);                                        \
            unsigned short h1 = f2bf(r1);                                      \
            unsigned short h2 = f2bf(r1 - bf2f(h1));                           \
            Fh[BUF][base + j] = h0;                                            \
            Fl[BUF][base + j] = h1;                                            \
            Fm[BUF][base + j] = h2;                                            \
        }                                                                      \
    }

    // prologue: features for step 0
    {
        const int l0 = d ? (LL - 1) : 0;
        DO_FEATURES(l0, 0)
    }
    __syncthreads();

    for (int step = 0; step < LL; ++step) {
        const int fb = step & 1;

        // ================= Phase A: GEMM + features(t+1) + emissions(t-1) ==
        f32x4 acc[2][2];
        #pragma unroll
        for (int mt = 0; mt < 2; ++mt)
            #pragma unroll
            for (int nt = 0; nt < 2; ++nt)
                acc[mt][nt] = (f32x4){0.f, 0.f, 0.f, 0.f};

#define WLOAD(B, P, KS)                                                        \
        {                                                                      \
            B[0] = *(const bf16x8*)((P) + (KS) * 96);                          \
            B[1] = *(const bf16x8*)((P) + (KS) * 96 + 32);                     \
            B[2] = *(const bf16x8*)((P) + (KS) * 96 + 64);                     \
        }
        // D = W' * A'  (same 6 products, same order as R9-R15)
#define GEMM6(B, NT)                                                           \
        {                                                                      \
            acc[0][NT] = __builtin_amdgcn_mfma_f32_16x16x32_bf16(B[0], a0[0], acc[0][NT], 0, 0, 0); \
            acc[0][NT] = __builtin_amdgcn_mfma_f32_16x16x32_bf16(B[0], a0[1], acc[0][NT], 0, 0, 0); \
            acc[0][NT] = __builtin_amdgcn_mfma_f32_16x16x32_bf16(B[1], a0[0], acc[0][NT], 0, 0, 0); \
            acc[0][NT] = __builtin_amdgcn_mfma_f32_16x16x32_bf16(B[1], a0[1], acc[0][NT], 0, 0, 0); \
            acc[0][NT] = __builtin_amdgcn_mfma_f32_16x16x32_bf16(B[2], a0[0], acc[0][NT], 0, 0, 0); \
            acc[0][NT] = __builtin_amdgcn_mfma_f32_16x16x32_bf16(B[0], a0[2], acc[0][NT], 0, 0, 0); \
            acc[1][NT] = __builtin_amdgcn_mfma_f32_16x16x32_bf16(B[0], a1[0], acc[1][NT], 0, 0, 0); \
            acc[1][NT] = __builtin_amdgcn_mfma_f32_16x16x32_bf16(B[0], a1[1], acc[1][NT], 0, 0, 0); \
            acc[1][NT] = __builtin_amdgcn_mfma_f32_16x16x32_bf16(B[1], a1[0], acc[1][NT], 0, 0, 0); \
            acc[1][NT] = __builtin_amdgcn_mfma_f32_16x16x32_bf16(B[1], a1[1], acc[1][NT], 0, 0, 0); \
            acc[1][NT] = __builtin_amdgcn_mfma_f32_16x16x32_bf16(B[2], a1[0], acc[1][NT], 0, 0, 0); \
            acc[1][NT] = __builtin_amdgcn_mfma_f32_16x16x32_bf16(B[0], a1[2], acc[1][NT], 0, 0, 0); \
        }

        {
            // full-Ks double buffer: 6 loads in flight per wave
            bf16x8 wbuf[2][2][3];
            #pragma unroll
            for (int nt = 0; nt < 2; ++nt)
                WLOAD(wbuf[0][nt], Wn[nt], 0)

            #pragma unroll
            for (int Ks = 0; Ks < 11; ++Ks) {
                const int cur = Ks & 1, nxt = cur ^ 1;
                if (Ks < 10) {
                    #pragma unroll
                    for (int nt = 0; nt < 2; ++nt)
                        WLOAD(wbuf[nxt][nt], Wn[nt], Ks + 1)
                }
                bf16x8 a0[3], a1[3];
                if (Ks < 7) {
                    const int ko = Ks * 32 + quad * 8;
                    a0[0] = *(const bf16x8*)&Fh[fb][ml * FSTR + ko];
                    a0[1] = *(const bf16x8*)&Fl[fb][ml * FSTR + ko];
                    a0[2] = *(const bf16x8*)&Fm[fb][ml * FSTR + ko];
                    a1[0] = *(const bf16x8*)&Fh[fb][(16 + ml) * FSTR + ko];
                    a1[1] = *(const bf16x8*)&Fl[fb][(16 + ml) * FSTR + ko];
                    a1[2] = *(const bf16x8*)&Fm[fb][(16 + ml) * FSTR + ko];
                } else {
                    const int ko = (Ks - 7) * 32 + quad * 8;
                    a0[0] = *(const bf16x8*)&Hh[ml * HSTR + ko];
                    a0[1] = *(const bf16x8*)&Hl[ml * HSTR + ko];
                    a0[2] = *(const bf16x8*)&Hm[ml * HSTR + ko];
                    a1[0] = *(const bf16x8*)&Hh[(16 + ml) * HSTR + ko];
                    a1[1] = *(const bf16x8*)&Hl[(16 + ml) * HSTR + ko];
                    a1[2] = *(const bf16x8*)&Hm[(16 + ml) * HSTR + ko];
                }
                GEMM6(wbuf[cur][0], 0)
                GEMM6(wbuf[cur][1], 1)
            }
        }
#undef WLOAD
#undef GEMM6

        // features for step+1 into the other F buffer (disjoint from GEMM reads)
        if (step + 1 < LL) {
            const int lnext = d ? (LL - 2 - step) : (step + 1);
            DO_FEATURES(lnext, (step + 1) & 1)
        }
        // emissions for step-1 (reads H = h_{step-1}; H not written this phase)
        if (step > 0 && tid < 192) {
            const int lprev = d ? (LL - step) : (step - 1);
            int bb = tid / 6, r6 = tid % 6, t = r6 >> 1, seg = r6 & 1;
            int hb = bb * HSTR + seg * 64;
            const float* wfc = &Wfc_s[t * 128 + seg * 64];
            float s = 0.f;
            #pragma unroll
            for (int i = 0; i < 8; ++i) {
                u16x8 v0 = *(const u16x8*)&Hh[hb + i * 8];
                u16x8 v1 = *(const u16x8*)&Hl[hb + i * 8];
                u16x8 v2 = *(const u16x8*)&Hm[hb + i * 8];
                #pragma unroll
                for (int j = 0; j < 8; ++j) {
                    float h = bf2f(v0[j]) + bf2f(v1[j]) + bf2f(v2[j]);
                    s += h * wfc[i * 8 + j];
                }
            }
            s += __shfl_xor(s, 1);
            if (seg == 0)
                emis[(((b0 + bb) * LL) + lprev) * TT + t] = s;
        }

        __syncthreads();   // all F/H reads done; F[next] writes complete

        // ================= Phase B: gates in-register -> h into H ==========
        #pragma unroll
        for (int mt = 0; mt < 2; ++mt) {
            #pragma unroll
            for (int nt = 0; nt < 2; ++nt) {
                float zi = acc[mt][nt][0] + bIv[nt];
                float zf = acc[mt][nt][1] + bFv[nt];
                float zg = acc[mt][nt][2] + bGv[nt];
                float zo = acc[mt][nt][3] + bOv[nt];
                float cn = sigm(zf) * cst[mt][nt] + sigm(zi) * tanh_fast(zg);
                cst[mt][nt] = cn;
                float h = sigm(zo) * tanh_fast(cn);
                unsigned short h0 = f2bf(h);
                float r1 = h - bf2f(h0);
                unsigned short h1 = f2bf(r1);
                unsigned short h2 = f2bf(r1 - bf2f(h1));
                int idx = (mt * 16 + ml) * HSTR + un[nt];
                Hh[idx] = h0;
                Hl[idx] = h1;
                Hm[idx] = h2;
            }
        }
        __syncthreads();   // h_step visible for next GEMM / emissions
    }

    // epilogue: emissions for the last step
    if (tid < 192) {
        const int llast = d ? 0 : (LL - 1);
        int bb = tid / 6, r6 = tid % 6, t = r6 >> 1, seg = r6 & 1;
        int hb = bb * HSTR + seg * 64;
        const float* wfc = &Wfc_s[t * 128 + seg * 64];
        float s = 0.f;
        #pragma unroll
        for (int i = 0; i < 8; ++i) {
            u16x8 v0 = *(const u16x8*)&Hh[hb + i * 8];
            u16x8 v1 = *(const u16x8*)&Hl[hb + i * 8];
            u16x8 v2 = *(const u16x8*)&Hm[hb + i * 8];
            #pragma unroll
            for (int j = 0; j < 8; ++j) {
                float h = bf2f(v0[j]) + bf2f(v1[j]) + bf2f(v2[j]);
                s += h * wfc[i * 8 + j];
            }
        }
        s += __shfl_xor(s, 1);
        if (seg == 0)
            emis[(((b0 + bb) * LL) + llast) * TT + t] = s;
    }
#undef DO_FEATURES
}

// ---------------------------------------------------------------------------
// Kernel 3: Viterbi decode. One thread per batch row.
// ---------------------------------------------------------------------------
__global__ void viterbi_kernel(const int* __restrict__ x, const float* __restrict__ ws,
                               const float* __restrict__ trans,
                               const float* __restrict__ start_t,
                               const float* __restrict__ end_t,
                               float* __restrict__ out)
{
    int b = blockIdx.x * blockDim.x + threadIdx.x;
    if (b >= BB) return;
    const float* eF = ws + WS_EMIS;
    const float* eB = ws + WS_EMIS + BB * LL * TT;
    const float eb0 = ws[WS_EB + 0], eb1 = ws[WS_EB + 1], eb2 = ws[WS_EB + 2];
    float tr[9];
    #pragma unroll
    for (int i = 0; i < 9; ++i) tr[i] = trans[i];

    int base = b * LL * TT;
    float s0 = start_t[0] + eF[base + 0] + eB[base + 0] + eb0;
    float s1 = start_t[1] + eF[base + 1] + eB[base + 1] + eb1;
    float s2 = start_t[2] + eF[base + 2] + eB[base + 2] + eb2;

    unsigned hist[LL - 1];
    unsigned maskbits = 0;

    #pragma unroll
    for (int l = 1; l < LL; ++l) {
        bool m = x[(b * LL + l) * WW + 2] > 0;
        if (m) maskbits |= (1u << l);
        int idx = base + l * TT;
        float e0 = eF[idx + 0] + eB[idx + 0] + eb0;
        float e1 = eF[idx + 1] + eB[idx + 1] + eb1;
        float e2 = eF[idx + 2] + eB[idx + 2] + eb2;

        float ns[3]; int pt[3];
        #pragma unroll
        for (int nt = 0; nt < 3; ++nt) {
            float c0 = s0 + tr[0 * 3 + nt];
            float c1 = s1 + tr[1 * 3 + nt];
            float c2 = s2 + tr[2 * 3 + nt];
            int p = 0; float bc = c0;
            if (c1 > bc) { bc = c1; p = 1; }   // strict '>': first-index argmax
            if (c2 > bc) { bc = c2; p = 2; }
            ns[nt] = bc; pt[nt] = p;
        }
        ns[0] += e0; ns[1] += e1; ns[2] += e2;
        hist[l - 1] = (unsigned)pt[0] | ((unsigned)pt[1] << 2) | ((unsigned)pt[2] << 4);
        if (m) { s0 = ns[0]; s1 = ns[1]; s2 = ns[2]; }
    }
    s0 += end_t[0]; s1 += end_t[1]; s2 += end_t[2];
    float best = s0; int last = 0;
    if (s1 > best) { best = s1; last = 1; }
    if (s2 > best) { best = s2; last = 2; }

    out[b] = best;
    float* tags = out + BB + b * LL;
    int tag = last;
    tags[LL - 1] = (float)last;
    #pragma unroll
    for (int l = LL - 1; l >= 1; --l) {
        int prev = (int)((hist[l - 1] >> (2 * tag)) & 3u);
        if (maskbits & (1u << l)) tag = prev;
        tags[l - 1] = (float)tag;
    }
}

// ---------------------------------------------------------------------------
extern "C" void kernel_launch(void* const* d_in, const int* in_sizes, int n_in,
                              void* d_out, int out_size, void* d_ws, size_t ws_size,
                              hipStream_t stream)
{
    const int*   x      = (const int*)  d_in[0];
    const float* emb    = (const float*)d_in[1];
    const float* conv_w = (const float*)d_in[2];
    const float* conv_b = (const float*)d_in[3];
    const float* bn1_g  = (const float*)d_in[4];
    const float* bn1_b  = (const float*)d_in[5];
    const float* bn1_m  = (const float*)d_in[6];
    const float* bn1_v  = (const float*)d_in[7];
    const float* w_ih_f = (const float*)d_in[8];
    const float* w_hh_f = (const float*)d_in[9];
    const float* b_f    = (const float*)d_in[10];
    const float* w_ih_b = (const float*)d_in[11];
    const float* w_hh_b = (const float*)d_in[12];
    const float* b_b    = (const float*)d_in[13];
    const float* bn2_g  = (const float*)d_in[14];
    const float* bn2_b  = (const float*)d_in[15];
    const float* bn2_m  = (const float*)d_in[16];
    const float* bn2_v  = (const float*)d_in[17];
    const float* fc_w   = (const float*)d_in[18];
    const float* fc_b   = (const float*)d_in[19];
    const float* trans  = (const float*)d_in[20];
    const float* start_t= (const float*)d_in[21];
    const float* end_t  = (const float*)d_in[22];

    float* ws  = (float*)d_ws;
    float* out = (float*)d_out;

    prep_kernel<<<256, 256, 0, stream>>>(emb, conv_w, conv_b,
                                         bn1_g, bn1_b, bn1_m, bn1_v,
                                         w_ih_f, w_hh_f, b_f,
                                         w_ih_b, w_hh_b, b_b,
                                         bn2_g, bn2_b, bn2_m, bn2_v,
                                         fc_w, fc_b, ws);
    lstm_kernel<<<256, 1024, 0, stream>>>(x, ws);
    viterbi_kernel<<<16, 256, 0, stream>>>(x, ws, trans, start_t, end_t, out);
}